// Round 10
// baseline (514.097 us; speedup 1.0000x reference)
//
#include <hip/hip_runtime.h>

// Double bilinear grid_sample (align_corners=False, zeros padding).
// feature: [8,64,256,256] f32 NCHW; grid: [8,256,256,2] f32.
//
// Split algorithm (r8): first = GS(feat,grid); out = GS(first,grid) ->
// 4+4 feature gathers/pt (fused r3 paid 16) and zero random grid
// gathers. FETCH is near-compulsory (97-119 MB/pass). r8/r9 were
// latency-bound (VALUBusy 15%): the 4-deep per-point load runs gave
// per-wave MLP ~4 (r3's fused loop: 16-deep runs, MLP 16).
// r10: LOOP INTERCHANGE to rebuild r3's proven issue shape inside the
// split -- corner e OUTER, point s INNER fully unrolled with 16 named
// accumulators: each e-pass issues 16 INDEPENDENT loads (addresses
// depend only on LDS descs) as one back-to-back run, then 16 fmas
// consume. 4 runs x 16-deep = r3's MLP at half the load count.
// Per-point corner order e=0..3 per acc unchanged -> bit-identical.
//
// Budget: harness 512 MiB re-poison fill (~80 us, immovable) +
// transpose (<78 us, near roofline) + gs1 + gs2.
//
// K1: transpose NCHW -> grouped NHWC16 [n][4][65536 px][16 ch].
// K2 (gs1): first[n][g][p][c] = sum_k wk(p) * fg[n][g][corner_k(p)][c].
// K3 (gs2): out[n][g*16+c][p]  = sum_k wk(p) * first[n][g][corner_k(p)][c].
// Both: blockIdx.x&7 = n (XCD pin), gridDim.y = 4 groups x-fastest
// -> 4 MB live slice per XCD L2.

#define GS_N 8
#define GS_C 64
#define GS_H 256
#define GS_W 256
#define GS_HW (GS_H * GS_W)
#define GS_IMG (GS_C * GS_HW)
#define GS_G 4                 // channel groups
#define GS_GC 16               // channels per group

typedef float f4v __attribute__((ext_vector_type(4)));

__global__ __launch_bounds__(256) void transpose_nchw_to_g16(
        const float* __restrict__ src, float* __restrict__ dst) {
    int b   = blockIdx.x;               // 2048 blocks: 256 hw x 64 c tile
    int n   = b >> 8;
    int hw0 = (b & 255) << 8;

    // Flat 64 KiB: row c = floats [c*256, c*256+256) as 64 float4 slots;
    // logical slot s of row c lives at phys slot s ^ (c>>3).
    __shared__ float lt[GS_C * 256];

    const float* sp = src + (size_t)n * GS_IMG + hw0;

    int l  = threadIdx.x & 63;
    int wv = threadIdx.x >> 6;

    #pragma unroll
    for (int t = 0; t < 16; ++t) {
        int c = (wv << 4) + t;
        f4v v = __builtin_nontemporal_load(
                    (const f4v*)(sp + ((size_t)c << 16) + (l << 2)));
        int s = l ^ (c >> 3);           // swizzled float4 slot
        *(f4v*)&lt[(c << 8) + (s << 2)] = v;
    }
    __syncthreads();

    int c4  = threadIdx.x & 15;
    int h0  = threadIdx.x >> 4;
    int g   = c4 >> 2;
    int cl0 = (c4 & 3) << 2;
    int swz = c4 >> 1;                  // == (4*c4+k)>>3 for k=0..3
    int c0  = c4 << 2;
    float* dp = dst + ((size_t)(n * GS_G + g) << 20)   // 4 MB slice
              + ((size_t)hw0 << 4) + cl0;
    #pragma unroll
    for (int t = 0; t < 16; ++t) {
        int hh  = h0 + (t << 4);
        int col = (((hh >> 2) ^ swz) << 2) | (hh & 3);  // float idx in row
        f4v v;
        v.x = lt[((c0 + 0) << 8) + col];
        v.y = lt[((c0 + 1) << 8) + col];
        v.z = lt[((c0 + 2) << 8) + col];
        v.w = lt[((c0 + 3) << 8) + col];
        __builtin_nontemporal_store(v, (f4v*)(dp + ((size_t)hh << 4)));
    }
}

__device__ __forceinline__ void corner_setup(float gx, float gy,
        int& x0, int& y0, float& w00, float& w01, float& w10, float& w11) {
    // ix = ((gx+1)*256 - 1)*0.5 = gx*128 + 127.5
    float ix = fmaf(gx, 128.0f, 127.5f);
    float iy = fmaf(gy, 128.0f, 127.5f);
    float fx0 = floorf(ix), fy0 = floorf(iy);
    float fx = ix - fx0, fy = iy - fy0;
    x0 = (int)fx0; y0 = (int)fy0;
    int x1 = x0 + 1, y1 = y0 + 1;
    float mx0 = (x0 >= 0 && x0 < GS_W) ? 1.0f : 0.0f;
    float mx1 = (x1 >= 0 && x1 < GS_W) ? 1.0f : 0.0f;
    float my0 = (y0 >= 0 && y0 < GS_H) ? 1.0f : 0.0f;
    float my1 = (y1 >= 0 && y1 < GS_H) ? 1.0f : 0.0f;
    w00 = (1.0f - fx) * (1.0f - fy) * mx0 * my0;
    w01 = fx * (1.0f - fy) * mx1 * my0;
    w10 = (1.0f - fx) * fy * mx0 * my1;
    w11 = fx * fy * mx1 * my1;
}

// Phase 1 (shared shape): thread = point; 4 descriptors into LDS.
__device__ __forceinline__ void build_descs(
        int2 (*s_desc)[4], const float* __restrict__ grid, int n, int p0) {
    int pt = threadIdx.x;
    float2 gp = ((const float2*)grid)[(size_t)n * GS_HW + p0 + pt];
    int x0, y0; float w00, w01, w10, w11;
    corner_setup(gp.x, gp.y, x0, y0, w00, w01, w10, w11);
    int x0c = min(max(x0, 0), GS_W - 1), x1c = min(max(x0 + 1, 0), GS_W - 1);
    int y0c = min(max(y0, 0), GS_H - 1), y1c = min(max(y0 + 1, 0), GS_H - 1);
    // byte offset of the 64 B group row: pixel * 16 ch * 4 B
    s_desc[pt][0] = make_int2((y0c * GS_W + x0c) << 6, __float_as_int(w00));
    s_desc[pt][1] = make_int2((y0c * GS_W + x1c) << 6, __float_as_int(w01));
    s_desc[pt][2] = make_int2((y1c * GS_W + x0c) << 6, __float_as_int(w10));
    s_desc[pt][3] = make_int2((y1c * GS_W + x1c) << 6, __float_as_int(w11));
}

__global__ __launch_bounds__(256) void gs_level1(
        const float* __restrict__ fg, const float* __restrict__ grid,
        float* __restrict__ first) {
    int bx  = blockIdx.x;              // 2048
    int g   = blockIdx.y;              // group, x-fastest dispatch
    int n   = bx & 7;                  // XCD pin (2048 % 8 == 0)
    int p0  = (bx >> 3) << 8;          // 256 points = one output row

    __shared__ int2 s_desc[256][4];

    build_descs(s_desc, grid, n, p0);
    __syncthreads();

    // Phase 2: lane = (pt-quartet ps, channel). e OUTER, s fully
    // unrolled: each e-pass = one 16-deep independent load run.
    int lane = threadIdx.x & 63;
    int wave = threadIdx.x >> 6;
    int ch4  = (lane & 15) << 2;
    int ps   = lane >> 4;
    const char* fbc = (const char*)(fg + ((size_t)(n * GS_G + g) << 20)) + ch4;
    float* fw = first + ((size_t)(n * GS_G + g) << 20) + (size_t)p0 * GS_GC
              + (lane & 15);

    float acc[16];
    #pragma unroll
    for (int s = 0; s < 16; ++s) acc[s] = 0.0f;

    #pragma unroll
    for (int e = 0; e < 4; ++e) {
        #pragma unroll
        for (int s = 0; s < 16; ++s) {      // 16 independent loads: one run
            int sl = (wave << 6) + (s << 2) + ps;
            int2 d = s_desc[sl][e];         // 16-lane broadcast, conflict-free
            float v = *(const float*)(fbc + (size_t)(unsigned)d.x);
            acc[s] = fmaf(__int_as_float(d.y), v, acc[s]);
        }
    }

    // contiguous 256 B per wave store instr; nt (L2 kept for gathers)
    #pragma unroll
    for (int s = 0; s < 16; ++s) {
        int sl = (wave << 6) + (s << 2) + ps;
        __builtin_nontemporal_store(acc[s], fw + sl * GS_GC);
    }
}

__global__ __launch_bounds__(256) void gs_level2(
        const float* __restrict__ first, const float* __restrict__ grid,
        float* __restrict__ out) {
    int bx  = blockIdx.x;              // 2048
    int g   = blockIdx.y;
    int n   = bx & 7;
    int idx = bx >> 3;                 // 0..255 = output row y
    int p0  = idx << 8;

    __shared__ int2  s_desc[256][4];
    __shared__ float tile[GS_GC][257]; // [ch][point]; (ch+pt)%32 ~2-way

    build_descs(s_desc, grid, n, p0);
    __syncthreads();

    int lane = threadIdx.x & 63;
    int wave = threadIdx.x >> 6;
    int ch4  = (lane & 15) << 2;
    int ps   = lane >> 4;
    const char* fbc = (const char*)(first + ((size_t)(n * GS_G + g) << 20)) + ch4;

    float acc[16];
    #pragma unroll
    for (int s = 0; s < 16; ++s) acc[s] = 0.0f;

    #pragma unroll
    for (int e = 0; e < 4; ++e) {
        #pragma unroll
        for (int s = 0; s < 16; ++s) {      // 16-deep independent load run
            int sl = (wave << 6) + (s << 2) + ps;
            int2 d = s_desc[sl][e];
            float v = *(const float*)(fbc + (size_t)(unsigned)d.x);
            acc[s] = fmaf(__int_as_float(d.y), v, acc[s]);
        }
    }
    #pragma unroll
    for (int s = 0; s < 16; ++s) {
        int sl = (wave << 6) + (s << 2) + ps;
        tile[lane & 15][sl] = acc[s];
    }
    __syncthreads();

    // coalesced NCHW write: full 256-px row per channel, nt
    float* ob = out + (size_t)n * GS_IMG + ((size_t)(g * GS_GC) << 16)
              + ((size_t)idx << 8);
    #pragma unroll
    for (int c = 0; c < GS_GC; ++c)
        __builtin_nontemporal_store(tile[c][threadIdx.x],
                                    ob + ((size_t)c << 16) + threadIdx.x);
}

extern "C" void kernel_launch(void* const* d_in, const int* in_sizes, int n_in,
                              void* d_out, int out_size, void* d_ws, size_t ws_size,
                              hipStream_t stream) {
    const float* feature = (const float*)d_in[0];
    const float* grid    = (const float*)d_in[1];
    float*       out     = (float*)d_out;
    float*       fg      = (float*)d_ws;                    // 128 MiB grouped feat
    float*       first   = (float*)d_ws + ((size_t)1 << 25); // +128 MiB grouped first

    transpose_nchw_to_g16<<<dim3(GS_N * GS_HW / 256), dim3(256), 0, stream>>>(feature, fg);
    gs_level1<<<dim3(GS_N * GS_HW / 256, GS_G), dim3(256), 0, stream>>>(fg, grid, first);
    gs_level2<<<dim3(GS_N * GS_HW / 256, GS_G), dim3(256), 0, stream>>>(first, grid, out);
}

// Round 11
// 375.569 us; speedup vs baseline: 1.3688x; 1.3688x over previous
//
#include <hip/hip_runtime.h>

// Double bilinear grid_sample (align_corners=False, zeros padding), fused.
// feature: [8,64,256,256] f32 NCHW; grid: [8,256,256,2] f32.
//
// FINAL (= r3, the session optimum; r4-r10's restructures all regressed):
// K1: transpose feature NCHW -> grouped NHWC16: [n][4][65536 px][16 ch].
//     256hw x 64c tiles, 1 KB contiguous reads (nt), XOR-swizzled LDS,
//     16 KB contiguous write per (block, group).
// K2: fused double-sample, channel-split for L2 residency: gridDim.y = 4
//     channel groups, dispatched x-fastest -> each XCD's live working set
//     is its n's 4 MB group slice (fits the 4 MB XCD L2). Phase 1
//     (thread = point x corner): 16 {byte-off, weight} descriptors per
//     point, one 8 B grid gather per thread. Phase 2 (lane = 4 pts x
//     16 ch): 64 B coalesced gathers + fma -- 16-deep load runs whose
//     addresses derive only from LDS descs (the shape the compiler
//     schedules best; do not restructure). Output staged via LDS for
//     coalesced NCHW stores (nt). blockIdx.x&7 = n pins each n's slice
//     to one XCD L2.
//
// Measured budget at this configuration (~377 us total): harness 512 MiB
// workspace re-poison fill ~80-160 us (immovable), transpose <78 us
// (near stream roofline), gs_fused ~170 us (TA/latency-balanced local
// optimum: VALUBusy 57%, HBM 27%, L2 ~37%, conflicts 0).

#define GS_N 8
#define GS_C 64
#define GS_H 256
#define GS_W 256
#define GS_HW (GS_H * GS_W)
#define GS_IMG (GS_C * GS_HW)
#define GS_G 4                 // channel groups
#define GS_GC 16               // channels per group

typedef float f4v __attribute__((ext_vector_type(4)));

__global__ __launch_bounds__(256) void transpose_nchw_to_g16(
        const float* __restrict__ src, float* __restrict__ dst) {
    int b   = blockIdx.x;               // 2048 blocks: 256 hw x 64 c tile
    int n   = b >> 8;
    int hw0 = (b & 255) << 8;

    // Flat 64 KiB: row c = floats [c*256, c*256+256) as 64 float4 slots;
    // logical slot s of row c lives at phys slot s ^ (c>>3).
    __shared__ float lt[GS_C * 256];

    const float* sp = src + (size_t)n * GS_IMG + hw0;

    int l  = threadIdx.x & 63;
    int wv = threadIdx.x >> 6;

    // ---- Phase A: wave = one channel per instruction; 1 KB contiguous
    // nt read (feature is dead after this kernel).
    #pragma unroll
    for (int t = 0; t < 16; ++t) {
        int c = (wv << 4) + t;
        f4v v = __builtin_nontemporal_load(
                    (const f4v*)(sp + ((size_t)c << 16) + (l << 2)));
        int s = l ^ (c >> 3);           // swizzled float4 slot
        *(f4v*)&lt[(c << 8) + (s << 2)] = v;
    }
    __syncthreads();

    // ---- Phase B: write grouped NHWC16. c4 = float4 group of channels
    // [4*c4, 4*c4+4) = group g = c4>>2, in-row float offset (c4&3)*4.
    int c4  = threadIdx.x & 15;
    int h0  = threadIdx.x >> 4;
    int g   = c4 >> 2;
    int cl0 = (c4 & 3) << 2;
    int swz = c4 >> 1;                  // == (4*c4+k)>>3 for k=0..3
    int c0  = c4 << 2;
    float* dp = dst + ((size_t)(n * GS_G + g) << 20)   // 4 MB slice
              + ((size_t)hw0 << 4) + cl0;
    #pragma unroll
    for (int t = 0; t < 16; ++t) {
        int hh  = h0 + (t << 4);
        int col = (((hh >> 2) ^ swz) << 2) | (hh & 3);  // float idx in row
        f4v v;
        v.x = lt[((c0 + 0) << 8) + col];
        v.y = lt[((c0 + 1) << 8) + col];
        v.z = lt[((c0 + 2) << 8) + col];
        v.w = lt[((c0 + 3) << 8) + col];
        *(f4v*)(dp + ((size_t)hh << 4)) = v;
    }
}

__device__ __forceinline__ void corner_setup(float gx, float gy,
        int& x0, int& y0, float& w00, float& w01, float& w10, float& w11) {
    // ix = ((gx+1)*256 - 1)*0.5 = gx*128 + 127.5
    float ix = fmaf(gx, 128.0f, 127.5f);
    float iy = fmaf(gy, 128.0f, 127.5f);
    float fx0 = floorf(ix), fy0 = floorf(iy);
    float fx = ix - fx0, fy = iy - fy0;
    x0 = (int)fx0; y0 = (int)fy0;
    int x1 = x0 + 1, y1 = y0 + 1;
    float mx0 = (x0 >= 0 && x0 < GS_W) ? 1.0f : 0.0f;
    float mx1 = (x1 >= 0 && x1 < GS_W) ? 1.0f : 0.0f;
    float my0 = (y0 >= 0 && y0 < GS_H) ? 1.0f : 0.0f;
    float my1 = (y1 >= 0 && y1 < GS_H) ? 1.0f : 0.0f;
    w00 = (1.0f - fx) * (1.0f - fy) * mx0 * my0;
    w01 = fx * (1.0f - fy) * mx1 * my0;
    w10 = (1.0f - fx) * fy * mx0 * my1;
    w11 = fx * fy * mx1 * my1;
}

__global__ __launch_bounds__(256) void gs_fused(
        const float* __restrict__ fg, const float* __restrict__ grid,
        float* __restrict__ out) {
    int bx  = blockIdx.x;              // 8192
    int g   = blockIdx.y;              // channel group (x-fastest dispatch)
    int n   = bx & 7;                  // XCD pin: (bx + 8192*g) % 8 == bx % 8
    int idx = bx >> 3;                 // 0..1023
    int p0  = (n << 16) + (idx << 6);  // first point (n,ho,wo0)

    __shared__ int2  s_desc[64][17];   // [point][entry] {byte_off, weight}
    __shared__ float tile[GS_GC][65];  // [ch-in-group][point]

    const float2* g2 = (const float2*)grid + (size_t)n * (size_t)GS_HW;

    // ---- Phase 1: all 256 threads; thread = (point, corner k).
    {
        int pt = threadIdx.x >> 2;
        int k  = threadIdx.x & 3;
        float2 gp = ((const float2*)grid)[p0 + pt];   // 4-thread broadcast
        int ox0, oy0; float w00, w01, w10, w11;
        corner_setup(gp.x, gp.y, ox0, oy0, w00, w01, w10, w11);
        int x0c = min(max(ox0, 0), GS_W - 1), x1c = min(max(ox0 + 1, 0), GS_W - 1);
        int y0c = min(max(oy0, 0), GS_H - 1), y1c = min(max(oy0 + 1, 0), GS_H - 1);
        int   qx = (k & 1) ? x1c : x0c;               // corner order 00,01,10,11
        int   qy = (k >> 1) ? y1c : y0c;
        float wk = (k == 0) ? w00 : (k == 1) ? w01 : (k == 2) ? w10 : w11;
        float2 gi = g2[qy * GS_W + qx];               // 8 B gather, L2-resident
        int ix0, iy0; float u00, u01, u10, u11;
        corner_setup(gi.x, gi.y, ix0, iy0, u00, u01, u10, u11);
        int a0 = min(max(ix0, 0), GS_W - 1), a1 = min(max(ix0 + 1, 0), GS_W - 1);
        int b0 = min(max(iy0, 0), GS_H - 1), b1 = min(max(iy0 + 1, 0), GS_H - 1);
        // byte offset of the 64 B group row: pixel * 16 ch * 4 B
        s_desc[pt][k * 4 + 0] = make_int2((b0 * GS_W + a0) << 6, __float_as_int(wk * u00));
        s_desc[pt][k * 4 + 1] = make_int2((b0 * GS_W + a1) << 6, __float_as_int(wk * u01));
        s_desc[pt][k * 4 + 2] = make_int2((b1 * GS_W + a0) << 6, __float_as_int(wk * u10));
        s_desc[pt][k * 4 + 3] = make_int2((b1 * GS_W + a1) << 6, __float_as_int(wk * u11));
    }
    __syncthreads();

    // ---- Phase 2: lane = (pt-oct, channel); 16 points per wave.
    {
        int lane = threadIdx.x & 63;
        int wave = threadIdx.x >> 6;
        int ch4  = (lane & 15) << 2;   // byte offset of channel in row
        int ps   = lane >> 4;          // 0..3: point within quartet
        const char* fbc = (const char*)(fg + ((size_t)(n * GS_G + g) << 20));
        #pragma unroll 1
        for (int s = 0; s < 4; ++s) {
            int sl = wave * 16 + s * 4 + ps;
            float acc = 0.0f;
            #pragma unroll
            for (int e = 0; e < 16; ++e) {
                int2 d = s_desc[sl][e];                   // 16-lane broadcast
                float v = *(const float*)(fbc + (size_t)(d.x + ch4));  // 64 B/pt
                acc = fmaf(__int_as_float(d.y), v, acc);
            }
            tile[lane & 15][sl] = acc;
        }
    }
    __syncthreads();

    // ---- coalesced NCHW write, non-temporal (don't pollute L2 slice)
    int ho  = (p0 >> 8) & 255;
    int wo0 = p0 & 255;
    float* ob = out + (size_t)n * GS_IMG + ((size_t)(g * GS_GC) << 16)
              + (size_t)ho * GS_W + wo0;
    int w  = threadIdx.x & 63;
    int c0 = threadIdx.x >> 6;
    #pragma unroll
    for (int c = c0; c < GS_GC; c += 4)
        __builtin_nontemporal_store(tile[c][w], ob + ((size_t)c << 16) + w);
}

extern "C" void kernel_launch(void* const* d_in, const int* in_sizes, int n_in,
                              void* d_out, int out_size, void* d_ws, size_t ws_size,
                              hipStream_t stream) {
    const float* feature = (const float*)d_in[0];
    const float* grid    = (const float*)d_in[1];
    float*       out     = (float*)d_out;
    float*       fg      = (float*)d_ws;           // 128 MiB grouped-NHWC16

    dim3 block(256);

    transpose_nchw_to_g16<<<dim3(GS_N * GS_HW / 256), block, 0, stream>>>(feature, fg);
    gs_fused<<<dim3(GS_N * GS_HW / 64, GS_G), block, 0, stream>>>(fg, grid, out);
}